// Round 1
// baseline (401.046 us; speedup 1.0000x reference)
//
#include <hip/hip_runtime.h>
#include <hip/hip_bf16.h>
#include <math.h>

#define BB 64
#define FF 128
#define TT 4096
#define KK 13
#define NT (BB * TT)          // 262144 samples per k
#define SCALE0 0.08838834764831845f   // sqrt(1/128)
#define SCALEK 0.125f                  // sqrt(2/128)
#define MCD_C  6.14185100f             // (10/ln10)*sqrt(2)

// Compute the 13 DCT-II (ortho) cepstral coeffs of log1p(|mel[:,t]|) for one
// (b,t) column of both inputs. Basis generated via Chebyshev recurrence:
// b_{k+1} = 2*b1*b_k - b_{k-1}, b1 = cos(pi*(f+0.5)/128). Scales hoisted.
__device__ __forceinline__ void compute_ceps(const float* __restrict__ pT,
                                             const float* __restrict__ pP,
                                             float aT[KK], float aP[KK]) {
#pragma unroll
    for (int k = 0; k < KK; ++k) { aT[k] = 0.0f; aP[k] = 0.0f; }
#pragma unroll 8
    for (int f = 0; f < FF; ++f) {
        float xT = __logf(1.0f + fabsf(pT[(size_t)f * TT]));
        float xP = __logf(1.0f + fabsf(pP[(size_t)f * TT]));
        float b1 = __cosf(3.14159265358979f * ((float)f + 0.5f) * (1.0f / FF));
        aT[0] += xT;        aP[0] += xP;
        aT[1] += b1 * xT;   aP[1] += b1 * xP;
        float twob1 = b1 + b1;
        float bkm1 = 1.0f, bk = b1;
#pragma unroll
        for (int k = 2; k < KK; ++k) {
            float bn = twob1 * bk - bkm1;
            bkm1 = bk; bk = bn;
            aT[k] += bn * xT;  aP[k] += bn * xP;
        }
    }
    aT[0] *= SCALE0; aP[0] *= SCALE0;
#pragma unroll
    for (int k = 1; k < KK; ++k) { aT[k] *= SCALEK; aP[k] *= SCALEK; }
}

// Pass 1: read both mel tensors once, compute cepstra, optionally cache them
// to workspace planes c[k][b*T+t], and accumulate per-k sum / sumsq
// (wave shuffle -> LDS 4-wave combine -> 1 atomicAdd per quantity per block).
// sums layout: [0..12]=sumT [13..25]=sqT [26..38]=sumP [39..51]=sqP
template <bool STORE>
__global__ __launch_bounds__(256) void pass1_kernel(const float* __restrict__ melT,
                                                    const float* __restrict__ melP,
                                                    float* __restrict__ sums,
                                                    float* __restrict__ cT,
                                                    float* __restrict__ cP) {
    int g = blockIdx.x * 256 + threadIdx.x;   // g in [0, NT)
    int b = g >> 12;                          // / TT
    int t = g & (TT - 1);
    const float* pT = melT + (size_t)b * FF * TT + t;
    const float* pP = melP + (size_t)b * FF * TT + t;

    float aT[KK], aP[KK];
    compute_ceps(pT, pP, aT, aP);

    if (STORE) {
#pragma unroll
        for (int k = 0; k < KK; ++k) {
            cT[(size_t)k * NT + g] = aT[k];
            cP[(size_t)k * NT + g] = aP[k];
        }
    }

    __shared__ float red[4][52];
    int lane = threadIdx.x & 63;
    int wave = threadIdx.x >> 6;
#pragma unroll
    for (int k = 0; k < KK; ++k) {
        float s1 = aT[k], s2 = aT[k] * aT[k];
        float s3 = aP[k], s4 = aP[k] * aP[k];
        for (int off = 32; off > 0; off >>= 1) {
            s1 += __shfl_down(s1, off);
            s2 += __shfl_down(s2, off);
            s3 += __shfl_down(s3, off);
            s4 += __shfl_down(s4, off);
        }
        if (lane == 0) {
            red[wave][k]      = s1;
            red[wave][13 + k] = s2;
            red[wave][26 + k] = s3;
            red[wave][39 + k] = s4;
        }
    }
    __syncthreads();
    if (threadIdx.x < 52) {
        float v = red[0][threadIdx.x] + red[1][threadIdx.x] +
                  red[2][threadIdx.x] + red[3][threadIdx.x];
        atomicAdd(&sums[threadIdx.x], v);
    }
}

// Pass 2: per-block compute mean / 1/(std+1e-6) from the global sums (ddof=1),
// then per (b,t) read (or recompute) the 26 cepstra, normalized diff, MCD,
// hierarchical reduce, atomicAdd of block partial * 1/NT into d_out.
template <bool CACHED>
__global__ __launch_bounds__(256) void pass2_kernel(const float* __restrict__ melT,
                                                    const float* __restrict__ melP,
                                                    const float* __restrict__ sums,
                                                    const float* __restrict__ cT,
                                                    const float* __restrict__ cP,
                                                    float* __restrict__ out) {
    __shared__ float meanv[26];  // [0..12] true, [13..25] pred
    __shared__ float invsd[26];
    if (threadIdx.x < 26) {
        int arr = threadIdx.x / 13;
        int k   = threadIdx.x % 13;
        float s = sums[arr * 26 + k];
        float q = sums[arr * 26 + 13 + k];
        const float N = (float)NT;
        float m   = s / N;
        float var = (q - s * m) / (N - 1.0f);
        var = fmaxf(var, 0.0f);
        float sd = sqrtf(var) + 1e-6f;
        meanv[threadIdx.x] = m;
        invsd[threadIdx.x] = 1.0f / sd;
    }
    __syncthreads();

    int g = blockIdx.x * 256 + threadIdx.x;
    float aT[KK], aP[KK];
    if (CACHED) {
#pragma unroll
        for (int k = 0; k < KK; ++k) {
            aT[k] = cT[(size_t)k * NT + g];
            aP[k] = cP[(size_t)k * NT + g];
        }
    } else {
        int b = g >> 12;
        int t = g & (TT - 1);
        compute_ceps(melT + (size_t)b * FF * TT + t,
                     melP + (size_t)b * FF * TT + t, aT, aP);
    }

    float ss = 0.0f;
#pragma unroll
    for (int k = 0; k < KK; ++k) {
        float d = (aT[k] - meanv[k]) * invsd[k] -
                  (aP[k] - meanv[13 + k]) * invsd[13 + k];
        ss += d * d;
    }
    float mcd = MCD_C * sqrtf(ss);

    int lane = threadIdx.x & 63;
    int wave = threadIdx.x >> 6;
    for (int off = 32; off > 0; off >>= 1) mcd += __shfl_down(mcd, off);
    __shared__ float r2[4];
    if (lane == 0) r2[wave] = mcd;
    __syncthreads();
    if (threadIdx.x == 0) {
        float bs = r2[0] + r2[1] + r2[2] + r2[3];
        atomicAdd(out, bs * (1.0f / (float)NT));
    }
}

extern "C" void kernel_launch(void* const* d_in, const int* in_sizes, int n_in,
                              void* d_out, int out_size, void* d_ws, size_t ws_size,
                              hipStream_t stream) {
    const float* melT = (const float*)d_in[0];
    const float* melP = (const float*)d_in[1];
    float* out  = (float*)d_out;
    float* sums = (float*)d_ws;                       // 52 floats @ offset 0
    float* cT   = (float*)((char*)d_ws + 256);        // 13*NT floats
    float* cP   = cT + (size_t)KK * NT;               // 13*NT floats

    const size_t need = 256 + (size_t)2 * KK * NT * sizeof(float);  // ~27.3 MB
    const bool cached = ws_size >= need;

    hipMemsetAsync(d_ws, 0, 256, stream);             // zero sum accumulators
    hipMemsetAsync(d_out, 0, sizeof(float), stream);  // zero output accumulator

    const int grid = NT / 256;  // 1024 blocks, exact cover
    if (cached) {
        pass1_kernel<true><<<grid, 256, 0, stream>>>(melT, melP, sums, cT, cP);
        pass2_kernel<true><<<grid, 256, 0, stream>>>(melT, melP, sums, cT, cP, out);
    } else {
        pass1_kernel<false><<<grid, 256, 0, stream>>>(melT, melP, sums, cT, cP);
        pass2_kernel<false><<<grid, 256, 0, stream>>>(melT, melP, sums, cT, cP, out);
    }
}

// Round 2
// 296.459 us; speedup vs baseline: 1.3528x; 1.3528x over previous
//
#include <hip/hip_runtime.h>
#include <math.h>

#define BB 64
#define FF 128
#define TT 4096
#define KK 13
#define NT (BB * TT)            // 262144 columns per tensor
#define NP (NT / 2)             // 131072 threads, 2 columns each
#define SCALE0 0.08838834764831845f   // sqrt(1/128)
#define SCALEK 0.125f                  // sqrt(2/128)
#define MCD_C  6.14185100f             // (10/ln10)*sqrt(2)

// Macro lists: named accumulators defeat the compiler's array-demotion /
// occupancy-driven register squeeze that produced VGPR_Count=32 in round 1.
#define KLIST(X) X(0) X(1) X(2) X(3) X(4) X(5) X(6) X(7) X(8) X(9) X(10) X(11) X(12)
#define K12(X)        X(1) X(2) X(3) X(4) X(5) X(6) X(7) X(8) X(9) X(10) X(11) X(12)

// Pass 1: stream both mel tensors once (float2 per lane, coalesced), compute
// the 13 ortho-DCT cepstral coeffs per column via Chebyshev recurrence
// (b_{k+1} = 2*b1*b_k - b_{k-1}), cache cepstra to ws planes, and accumulate
// per-k sum / sumsq via wave shuffle -> LDS -> one atomicAdd per block.
// sums layout: [0..12]=sumT [13..25]=sqT [26..38]=sumP [39..51]=sqP
__global__ __launch_bounds__(256, 2) void pass1_kernel(
    const float* __restrict__ melT, const float* __restrict__ melP,
    float* __restrict__ sums, float* __restrict__ cT, float* __restrict__ cP)
{
    const int gp = blockIdx.x * 256 + threadIdx.x;   // [0, NP)
    const int g0 = gp << 1;                          // first of 2 columns
    const int b  = g0 >> 12;                         // / TT
    const int t0 = g0 & (TT - 1);                    // even, t0+1 < TT
    const float* pT = melT + (size_t)b * FF * TT + t0;
    const float* pP = melP + (size_t)b * FF * TT + t0;

#define DECLACC(i) float tx##i = 0.f, ty##i = 0.f, px##i = 0.f, py##i = 0.f;
    KLIST(DECLACC)

#pragma unroll 4
    for (int f = 0; f < FF; ++f) {
        const float2 vT = *(const float2*)(pT + (size_t)f * TT);
        const float2 vP = *(const float2*)(pP + (size_t)f * TT);
        float xTx = __logf(1.0f + fabsf(vT.x));
        float xTy = __logf(1.0f + fabsf(vT.y));
        float xPx = __logf(1.0f + fabsf(vP.x));
        float xPy = __logf(1.0f + fabsf(vP.y));

        float b1 = __cosf((3.14159265358979f / 128.0f) * ((float)f + 0.5f));
        float tw = b1 + b1;
        float b2  = fmaf(tw, b1,  -1.0f);
        float b3  = fmaf(tw, b2,  -b1);
        float b4  = fmaf(tw, b3,  -b2);
        float b5  = fmaf(tw, b4,  -b3);
        float b6  = fmaf(tw, b5,  -b4);
        float b7  = fmaf(tw, b6,  -b5);
        float b8  = fmaf(tw, b7,  -b6);
        float b9  = fmaf(tw, b8,  -b7);
        float b10 = fmaf(tw, b9,  -b8);
        float b11 = fmaf(tw, b10, -b9);
        float b12 = fmaf(tw, b11, -b10);

        tx0 += xTx; ty0 += xTy; px0 += xPx; py0 += xPy;
#define FMAK(i) tx##i = fmaf(b##i, xTx, tx##i); ty##i = fmaf(b##i, xTy, ty##i); \
                px##i = fmaf(b##i, xPx, px##i); py##i = fmaf(b##i, xPy, py##i);
        K12(FMAK)
#undef FMAK
    }

    tx0 *= SCALE0; ty0 *= SCALE0; px0 *= SCALE0; py0 *= SCALE0;
#define SCK(i) tx##i *= SCALEK; ty##i *= SCALEK; px##i *= SCALEK; py##i *= SCALEK;
    K12(SCK)
#undef SCK

    // cache cepstra: plane layout c[k][g], float2 per thread -> coalesced
#define STK(i) { ((float2*)(cT + (size_t)(i) * NT))[gp] = make_float2(tx##i, ty##i); \
                 ((float2*)(cP + (size_t)(i) * NT))[gp] = make_float2(px##i, py##i); }
    KLIST(STK)
#undef STK

    // per-k sum & sumsq over both columns -> wave reduce -> LDS -> atomic
    __shared__ float red[4][52];
    const int lane = threadIdx.x & 63;
    const int wave = threadIdx.x >> 6;
#define REDK(i) { \
        float s1 = tx##i + ty##i; \
        float s2 = fmaf(tx##i, tx##i, ty##i * ty##i); \
        float s3 = px##i + py##i; \
        float s4 = fmaf(px##i, px##i, py##i * py##i); \
        for (int o = 32; o > 0; o >>= 1) { \
            s1 += __shfl_down(s1, o); s2 += __shfl_down(s2, o); \
            s3 += __shfl_down(s3, o); s4 += __shfl_down(s4, o); } \
        if (lane == 0) { red[wave][i] = s1; red[wave][13 + i] = s2; \
                         red[wave][26 + i] = s3; red[wave][39 + i] = s4; } }
    KLIST(REDK)
#undef REDK
    __syncthreads();
    if (threadIdx.x < 52) {
        atomicAdd(&sums[threadIdx.x],
                  red[0][threadIdx.x] + red[1][threadIdx.x] +
                  red[2][threadIdx.x] + red[3][threadIdx.x]);
    }
}

// Pass 2: finalize mean / 1/(std+1e-6) (ddof=1) in LDS, stream the cached
// cepstra (27 MB), running-sum the normalized squared diff per column,
// mcd = C*sqrt(ss), hierarchical reduce, one atomicAdd per block.
__global__ __launch_bounds__(256, 2) void pass2_kernel(
    const float* __restrict__ sums, const float* __restrict__ cT,
    const float* __restrict__ cP, float* __restrict__ out)
{
    __shared__ float mT[13], iT[13], mP[13], iP[13];
    if (threadIdx.x < 26) {
        const int arr = threadIdx.x >= 13;
        const int k   = threadIdx.x - arr * 13;
        const float s = sums[arr * 26 + k];
        const float q = sums[arr * 26 + 13 + k];
        const float N = (float)NT;
        const float m = s / N;
        const float var = fmaxf((q - s * m) / (N - 1.0f), 0.0f);
        const float isd = 1.0f / (sqrtf(var) + 1e-6f);
        if (arr == 0) { mT[k] = m; iT[k] = isd; }
        else          { mP[k] = m; iP[k] = isd; }
    }
    __syncthreads();

    const int gp = blockIdx.x * 256 + threadIdx.x;   // [0, NP)
    float ssx = 0.0f, ssy = 0.0f;
#pragma unroll
    for (int k = 0; k < KK; ++k) {
        const float2 a = ((const float2*)(cT + (size_t)k * NT))[gp];
        const float2 p = ((const float2*)(cP + (size_t)k * NT))[gp];
        const float dx = (a.x - mT[k]) * iT[k] - (p.x - mP[k]) * iP[k];
        const float dy = (a.y - mT[k]) * iT[k] - (p.y - mP[k]) * iP[k];
        ssx = fmaf(dx, dx, ssx);
        ssy = fmaf(dy, dy, ssy);
    }
    float v = MCD_C * (sqrtf(ssx) + sqrtf(ssy));

    const int lane = threadIdx.x & 63;
    const int wave = threadIdx.x >> 6;
    for (int o = 32; o > 0; o >>= 1) v += __shfl_down(v, o);
    __shared__ float r2[4];
    if (lane == 0) r2[wave] = v;
    __syncthreads();
    if (threadIdx.x == 0) {
        atomicAdd(out, (r2[0] + r2[1] + r2[2] + r2[3]) * (1.0f / (float)NT));
    }
}

extern "C" void kernel_launch(void* const* d_in, const int* in_sizes, int n_in,
                              void* d_out, int out_size, void* d_ws, size_t ws_size,
                              hipStream_t stream) {
    const float* melT = (const float*)d_in[0];
    const float* melP = (const float*)d_in[1];
    float* out  = (float*)d_out;
    float* sums = (float*)d_ws;                    // 52 floats @ offset 0
    float* cT   = (float*)((char*)d_ws + 256);     // 13*NT floats
    float* cP   = cT + (size_t)KK * NT;            // 13*NT floats
    // ws requirement ~27.3 MB — confirmed available in round 1 (WRITE_SIZE).

    hipMemsetAsync(d_ws, 0, 256, stream);                        // zero sums
    hipMemsetAsync(d_out, 0, out_size * sizeof(float), stream);  // zero output

    pass1_kernel<<<NP / 256, 256, 0, stream>>>(melT, melP, sums, cT, cP);
    pass2_kernel<<<NP / 256, 256, 0, stream>>>(sums, cT, cP, out);
}

// Round 3
// 291.559 us; speedup vs baseline: 1.3755x; 1.0168x over previous
//
#include <hip/hip_runtime.h>
#include <math.h>

#define BB 64
#define FF 128
#define TT 4096
#define KK 13
#define NT (BB * TT)          // 262144 columns per tensor (= mcd sample count)
#define NPAIR (NT / 2)        // 131072 column-pairs per tensor
#define SCALE0 0.08838834764831845f   // sqrt(1/128)
#define SCALEK 0.125f                  // sqrt(2/128)
#define MCD_C  6.14185100f             // (10/ln10)*sqrt(2)

// ws layout (bytes):
//   [0,    4096)  : 52 stat accumulators, each padded to its own 64B line
//                   slot j at float index j*16; j = tensor*26 + (k | 13+k)
//   [4096, 8192)  : 512 per-block mcd partials (pass2 -> pass3)
//   [8192, ...)   : cT planes (13*NT floats), then cP planes (13*NT floats)

#define KLIST(X) X(0) X(1) X(2) X(3) X(4) X(5) X(6) X(7) X(8) X(9) X(10) X(11) X(12)
#define K12(X)        X(1) X(2) X(3) X(4) X(5) X(6) X(7) X(8) X(9) X(10) X(11) X(12)

// Pass 1: 1024 blocks; blocks [0,512) stream melT, [512,1024) stream melP.
// Each thread: 2 adjacent t-columns (float2 loads) of ONE tensor -> 26 live
// accumulators (fits ~64 VGPR, no AGPR shuttle, unlike the 52-acc round-2
// version that got squeezed to VGPR=48 + accvgpr traffic at 2 waves/SIMD).
__global__ __launch_bounds__(256, 4) void pass1_kernel(
    const float* __restrict__ melT, const float* __restrict__ melP,
    float* __restrict__ sums, float* __restrict__ cT, float* __restrict__ cP)
{
    const int tensor = blockIdx.x >> 9;                       // 0=true 1=pred
    const int gp = ((blockIdx.x & 511) << 8) + threadIdx.x;   // [0, NPAIR)
    const float* __restrict__ src = tensor ? melP : melT;
    float* __restrict__ dst = tensor ? cP : cT;

    const int g0 = gp << 1;          // first column index
    const int b  = g0 >> 12;         // / TT
    const int t0 = g0 & (TT - 1);    // even
    const float* p = src + (size_t)b * (FF * TT) + t0;

#define DECLACC(i) float ax##i = 0.f, ay##i = 0.f;
    KLIST(DECLACC)
#undef DECLACC

#pragma unroll 4
    for (int f = 0; f < FF; ++f) {
        const float2 v = *(const float2*)(p + (size_t)f * TT);
        const float xx = __logf(1.0f + fabsf(v.x));
        const float xy = __logf(1.0f + fabsf(v.y));

        const float b1 = __cosf((3.14159265358979f / 128.0f) * ((float)f + 0.5f));
        const float tw = b1 + b1;
        const float b2  = fmaf(tw, b1,  -1.0f);
        const float b3  = fmaf(tw, b2,  -b1);
        const float b4  = fmaf(tw, b3,  -b2);
        const float b5  = fmaf(tw, b4,  -b3);
        const float b6  = fmaf(tw, b5,  -b4);
        const float b7  = fmaf(tw, b6,  -b5);
        const float b8  = fmaf(tw, b7,  -b6);
        const float b9  = fmaf(tw, b8,  -b7);
        const float b10 = fmaf(tw, b9,  -b8);
        const float b11 = fmaf(tw, b10, -b9);
        const float b12 = fmaf(tw, b11, -b10);

        ax0 += xx; ay0 += xy;
#define FMAK(i) ax##i = fmaf(b##i, xx, ax##i); ay##i = fmaf(b##i, xy, ay##i);
        K12(FMAK)
#undef FMAK
    }

    ax0 *= SCALE0; ay0 *= SCALE0;
#define SCK(i) ax##i *= SCALEK; ay##i *= SCALEK;
    K12(SCK)
#undef SCK

    // cache cepstra: plane k, float2 per thread, coalesced
#define STK(i) ((float2*)(dst + (size_t)(i) * NT))[gp] = make_float2(ax##i, ay##i);
    KLIST(STK)
#undef STK

    // per-k sum & sumsq -> wave shuffle -> LDS(4 waves) -> padded atomics
    __shared__ float red[4][26];
    const int lane = threadIdx.x & 63;
    const int wave = threadIdx.x >> 6;
#define REDK(i) { \
        float s = ax##i + ay##i; \
        float q = fmaf(ax##i, ax##i, ay##i * ay##i); \
        for (int o = 32; o > 0; o >>= 1) { \
            s += __shfl_down(s, o); q += __shfl_down(q, o); } \
        if (lane == 0) { red[wave][i] = s; red[wave][13 + i] = q; } }
    KLIST(REDK)
#undef REDK
    __syncthreads();
    if (threadIdx.x < 26) {
        const float v = red[0][threadIdx.x] + red[1][threadIdx.x] +
                        red[2][threadIdx.x] + red[3][threadIdx.x];
        atomicAdd(&sums[(tensor * 26 + threadIdx.x) * 16], v);  // own 64B line
    }
}

// Pass 2: finalize mean / 1/(std+1e-6) (ddof=1) in LDS, stream cached
// cepstra (27 MB, LLC-hot), per-column mcd, block partial -> plain store.
__global__ __launch_bounds__(256, 4) void pass2_kernel(
    const float* __restrict__ sums, const float* __restrict__ cT,
    const float* __restrict__ cP, float* __restrict__ partials)
{
    __shared__ float mT[13], iT[13], mP[13], iP[13];
    if (threadIdx.x < 26) {
        const int tns = threadIdx.x >= 13;
        const int k   = threadIdx.x - tns * 13;
        const float s = sums[(tns * 26 + k) * 16];
        const float q = sums[(tns * 26 + 13 + k) * 16];
        const float N = (float)NT;
        const float m = s / N;
        const float var = fmaxf((q - s * m) / (N - 1.0f), 0.0f);
        const float isd = 1.0f / (sqrtf(var) + 1e-6f);
        if (tns == 0) { mT[k] = m; iT[k] = isd; }
        else          { mP[k] = m; iP[k] = isd; }
    }
    __syncthreads();

    const int gp = blockIdx.x * 256 + threadIdx.x;   // [0, NPAIR)
    float ssx = 0.0f, ssy = 0.0f;
#pragma unroll
    for (int k = 0; k < KK; ++k) {
        const float2 a = ((const float2*)(cT + (size_t)k * NT))[gp];
        const float2 p = ((const float2*)(cP + (size_t)k * NT))[gp];
        const float dx = (a.x - mT[k]) * iT[k] - (p.x - mP[k]) * iP[k];
        const float dy = (a.y - mT[k]) * iT[k] - (p.y - mP[k]) * iP[k];
        ssx = fmaf(dx, dx, ssx);
        ssy = fmaf(dy, dy, ssy);
    }
    float v = MCD_C * (sqrtf(ssx) + sqrtf(ssy));

    const int lane = threadIdx.x & 63;
    const int wave = threadIdx.x >> 6;
    for (int o = 32; o > 0; o >>= 1) v += __shfl_down(v, o);
    __shared__ float r2[4];
    if (lane == 0) r2[wave] = v;
    __syncthreads();
    if (threadIdx.x == 0)
        partials[blockIdx.x] = r2[0] + r2[1] + r2[2] + r2[3];
}

// Pass 3: one block reduces the 512 partials and writes the mean.
__global__ __launch_bounds__(256) void pass3_kernel(
    const float* __restrict__ partials, float* __restrict__ out)
{
    float v = partials[threadIdx.x] + partials[threadIdx.x + 256];
    const int lane = threadIdx.x & 63;
    const int wave = threadIdx.x >> 6;
    for (int o = 32; o > 0; o >>= 1) v += __shfl_down(v, o);
    __shared__ float r2[4];
    if (lane == 0) r2[wave] = v;
    __syncthreads();
    if (threadIdx.x == 0)
        out[0] = (r2[0] + r2[1] + r2[2] + r2[3]) * (1.0f / (float)NT);
}

extern "C" void kernel_launch(void* const* d_in, const int* in_sizes, int n_in,
                              void* d_out, int out_size, void* d_ws, size_t ws_size,
                              hipStream_t stream) {
    const float* melT = (const float*)d_in[0];
    const float* melP = (const float*)d_in[1];
    float* out      = (float*)d_out;
    float* sums     = (float*)d_ws;                     // padded stats
    float* partials = (float*)((char*)d_ws + 4096);     // 512 floats
    float* cT       = (float*)((char*)d_ws + 8192);     // 13*NT floats
    float* cP       = cT + (size_t)KK * NT;             // 13*NT floats

    hipMemsetAsync(d_ws, 0, 4096, stream);              // zero stat accumulators

    pass1_kernel<<<1024, 256, 0, stream>>>(melT, melP, sums, cT, cP);
    pass2_kernel<<<512, 256, 0, stream>>>(sums, cT, cP, partials);
    pass3_kernel<<<1, 256, 0, stream>>>(partials, out);
}

// Round 4
// 287.432 us; speedup vs baseline: 1.3953x; 1.0144x over previous
//
#include <hip/hip_runtime.h>
#include <math.h>

#define BB 64
#define FF 128
#define TT 4096
#define KK 13
#define NT (BB * TT)          // 262144 columns per tensor (= mcd sample count)
#define NPAIR (NT / 2)        // 131072 column-pairs per tensor
#define MCD_C  6.14185100f    // (10/ln10)*sqrt(2)

// NOTE on scales: reference applies log1p (= ln2 * log2(1+x)) and per-k DCT
// scale sqrt(1/128) / sqrt(2/128). CMVN divides each k by its own std, so any
// per-k linear scale cancels exactly (epsilon 1e-6 placement shifts output by
// ~1e-5, far under threshold). We therefore accumulate raw log2-based,
// unscaled coefficients and normalize those — fewer VALU ops/iter.

// ws layout (bytes):
//   [0,    4096)  : 52 stat accumulators, each on its own 64B line
//   [4096, 8192)  : 512 per-block mcd partials (pass2 -> pass3)
//   [8192, ...)   : cT planes (13*NT floats), then cP planes (13*NT floats)

#define KLIST(X) X(0) X(1) X(2) X(3) X(4) X(5) X(6) X(7) X(8) X(9) X(10) X(11) X(12)
#define K12(X)        X(1) X(2) X(3) X(4) X(5) X(6) X(7) X(8) X(9) X(10) X(11) X(12)

// Pass 1: 1024 blocks; [0,512) stream melT, [512,1024) stream melP. Thread =
// 2 adjacent t-columns of one tensor -> 26 accumulators. amdgpu_waves_per_eu
// (4,4) pins target occupancy so the allocator actually spends ~128 VGPRs
// (rounds 1-3 all collapsed to VGPR_Count=32 + shuttle traffic without it).
__global__ __launch_bounds__(256)
__attribute__((amdgpu_waves_per_eu(4, 4)))
void pass1_kernel(
    const float* __restrict__ melT, const float* __restrict__ melP,
    float* __restrict__ sums, float* __restrict__ cT, float* __restrict__ cP)
{
    const int tensor = blockIdx.x >> 9;                       // 0=true 1=pred
    const int gp = ((blockIdx.x & 511) << 8) + threadIdx.x;   // [0, NPAIR)
    const float* __restrict__ src = tensor ? melP : melT;
    float* __restrict__ dst = tensor ? cP : cT;

    const int g0 = gp << 1;          // first column index
    const int b  = g0 >> 12;         // / TT
    const int t0 = g0 & (TT - 1);    // even
    const float* p = src + (size_t)b * (FF * TT) + t0;

#define DECLACC(i) float ax##i = 0.f, ay##i = 0.f;
    KLIST(DECLACC)
#undef DECLACC

    for (int f0 = 0; f0 < FF; f0 += 8) {
        // batch of 8 independent float2 loads -> 8 in flight per wave
        float2 v[8];
#pragma unroll
        for (int j = 0; j < 8; ++j)
            v[j] = *(const float2*)(p + (size_t)(f0 + j) * TT);

#pragma unroll
        for (int j = 0; j < 8; ++j) {
            const float xx = __log2f(1.0f + fabsf(v[j].x));
            const float xy = __log2f(1.0f + fabsf(v[j].y));

            const float b1 = __cosf((3.14159265358979f / 128.0f) *
                                    ((float)(f0 + j) + 0.5f));
            const float tw = b1 + b1;
            const float b2  = fmaf(tw, b1,  -1.0f);
            const float b3  = fmaf(tw, b2,  -b1);
            const float b4  = fmaf(tw, b3,  -b2);
            const float b5  = fmaf(tw, b4,  -b3);
            const float b6  = fmaf(tw, b5,  -b4);
            const float b7  = fmaf(tw, b6,  -b5);
            const float b8  = fmaf(tw, b7,  -b6);
            const float b9  = fmaf(tw, b8,  -b7);
            const float b10 = fmaf(tw, b9,  -b8);
            const float b11 = fmaf(tw, b10, -b9);
            const float b12 = fmaf(tw, b11, -b10);

            ax0 += xx; ay0 += xy;
#define FMAK(i) ax##i = fmaf(b##i, xx, ax##i); ay##i = fmaf(b##i, xy, ay##i);
            K12(FMAK)
#undef FMAK
        }
    }

    // cache (unscaled) cepstra: plane k, float2 per thread, coalesced
#define STK(i) ((float2*)(dst + (size_t)(i) * NT))[gp] = make_float2(ax##i, ay##i);
    KLIST(STK)
#undef STK

    // per-k sum & sumsq -> wave shuffle -> LDS(4 waves) -> padded atomics
    __shared__ float red[4][26];
    const int lane = threadIdx.x & 63;
    const int wave = threadIdx.x >> 6;
#define REDK(i) { \
        float s = ax##i + ay##i; \
        float q = fmaf(ax##i, ax##i, ay##i * ay##i); \
        for (int o = 32; o > 0; o >>= 1) { \
            s += __shfl_down(s, o); q += __shfl_down(q, o); } \
        if (lane == 0) { red[wave][i] = s; red[wave][13 + i] = q; } }
    KLIST(REDK)
#undef REDK
    __syncthreads();
    if (threadIdx.x < 26) {
        const float v = red[0][threadIdx.x] + red[1][threadIdx.x] +
                        red[2][threadIdx.x] + red[3][threadIdx.x];
        atomicAdd(&sums[(tensor * 26 + threadIdx.x) * 16], v);  // own 64B line
    }
}

// Pass 2: finalize mean / 1/(std+1e-6) (ddof=1) in LDS, stream cached
// cepstra (27 MB, LLC-hot), per-column mcd, block partial -> plain store.
__global__ __launch_bounds__(256, 4) void pass2_kernel(
    const float* __restrict__ sums, const float* __restrict__ cT,
    const float* __restrict__ cP, float* __restrict__ partials)
{
    __shared__ float mT[13], iT[13], mP[13], iP[13];
    if (threadIdx.x < 26) {
        const int tns = threadIdx.x >= 13;
        const int k   = threadIdx.x - tns * 13;
        const float s = sums[(tns * 26 + k) * 16];
        const float q = sums[(tns * 26 + 13 + k) * 16];
        const float N = (float)NT;
        const float m = s / N;
        const float var = fmaxf((q - s * m) / (N - 1.0f), 0.0f);
        const float isd = 1.0f / (sqrtf(var) + 1e-6f);
        if (tns == 0) { mT[k] = m; iT[k] = isd; }
        else          { mP[k] = m; iP[k] = isd; }
    }
    __syncthreads();

    const int gp = blockIdx.x * 256 + threadIdx.x;   // [0, NPAIR)
    float ssx = 0.0f, ssy = 0.0f;
#pragma unroll
    for (int k = 0; k < KK; ++k) {
        const float2 a = ((const float2*)(cT + (size_t)k * NT))[gp];
        const float2 p = ((const float2*)(cP + (size_t)k * NT))[gp];
        const float dx = (a.x - mT[k]) * iT[k] - (p.x - mP[k]) * iP[k];
        const float dy = (a.y - mT[k]) * iT[k] - (p.y - mP[k]) * iP[k];
        ssx = fmaf(dx, dx, ssx);
        ssy = fmaf(dy, dy, ssy);
    }
    float v = MCD_C * (sqrtf(ssx) + sqrtf(ssy));

    const int lane = threadIdx.x & 63;
    const int wave = threadIdx.x >> 6;
    for (int o = 32; o > 0; o >>= 1) v += __shfl_down(v, o);
    __shared__ float r2[4];
    if (lane == 0) r2[wave] = v;
    __syncthreads();
    if (threadIdx.x == 0)
        partials[blockIdx.x] = r2[0] + r2[1] + r2[2] + r2[3];
}

// Pass 3: one block reduces the 512 partials and writes the mean.
__global__ __launch_bounds__(256) void pass3_kernel(
    const float* __restrict__ partials, float* __restrict__ out)
{
    float v = partials[threadIdx.x] + partials[threadIdx.x + 256];
    const int lane = threadIdx.x & 63;
    const int wave = threadIdx.x >> 6;
    for (int o = 32; o > 0; o >>= 1) v += __shfl_down(v, o);
    __shared__ float r2[4];
    if (lane == 0) r2[wave] = v;
    __syncthreads();
    if (threadIdx.x == 0)
        out[0] = (r2[0] + r2[1] + r2[2] + r2[3]) * (1.0f / (float)NT);
}

extern "C" void kernel_launch(void* const* d_in, const int* in_sizes, int n_in,
                              void* d_out, int out_size, void* d_ws, size_t ws_size,
                              hipStream_t stream) {
    const float* melT = (const float*)d_in[0];
    const float* melP = (const float*)d_in[1];
    float* out      = (float*)d_out;
    float* sums     = (float*)d_ws;                     // padded stats
    float* partials = (float*)((char*)d_ws + 4096);     // 512 floats
    float* cT       = (float*)((char*)d_ws + 8192);     // 13*NT floats
    float* cP       = cT + (size_t)KK * NT;             // 13*NT floats

    hipMemsetAsync(d_ws, 0, 4096, stream);              // zero stat accumulators

    pass1_kernel<<<1024, 256, 0, stream>>>(melT, melP, sums, cT, cP);
    pass2_kernel<<<512, 256, 0, stream>>>(sums, cT, cP, partials);
    pass3_kernel<<<1, 256, 0, stream>>>(partials, out);
}